// Round 1
// baseline (78.208 us; speedup 1.0000x reference)
//
#include <hip/hip_runtime.h>

#define SEQ 2048
#define NH 8
#define NB 4
#define NQ 64           // queries per block
#define KP 4            // k-split per query
#define KPL (SEQ / KP)  // 512 keys per part

__device__ __forceinline__ float exp2_fast(float x) {
    float r;
    asm("v_exp_f32 %0, %1" : "=v"(r) : "v"(x));
    return r;
}

__global__ __launch_bounds__(256, 4)
void attn_d3_kernel(const float* __restrict__ x,
                    const float* __restrict__ Wq,
                    const float* __restrict__ Wk,
                    const float* __restrict__ Wv,
                    float* __restrict__ out) {
    __shared__ float xs[SEQ * 3];   // 24 KB: x for this batch b

    const int blk = blockIdx.x;
    const int qb  = blk & 31;       // 32 query-tiles per (b,h)
    const int bh  = blk >> 5;       // 0..31
    const int h   = bh & 7;
    const int b   = bh >> 3;

    const float* xb = x + b * (SEQ * 3);

    // stage x_b into LDS (float4 = 16B per lane, coalesced)
    {
        const float4* xg = (const float4*)xb;
        float4* xl = (float4*)xs;
        for (int i = threadIdx.x; i < (SEQ * 3 / 4); i += 256)
            xl[i] = xg[i];
    }

    // per-head 3x3 weights (wave-uniform h -> scalar loads)
    const float* wqp = Wq + h * 9;
    const float* wkp = Wk + h * 9;
    const float* wvp = Wv + h * 9;
    float wq_[9], wk_[9], wv_[9];
#pragma unroll
    for (int i = 0; i < 9; ++i) { wq_[i] = wqp[i]; wk_[i] = wkp[i]; wv_[i] = wvp[i]; }

    __syncthreads();

    const int qi   = threadIdx.x >> 2;  // 0..63
    const int part = threadIdx.x & 3;   // 0..3
    const int q    = qb * NQ + qi;

    // u = (x_q Wq) Wk^T * scale * log2(e)  -> scores in log2 domain
    const float xq0 = xs[q * 3 + 0], xq1 = xs[q * 3 + 1], xq2 = xs[q * 3 + 2];
    const float Q0 = xq0 * wq_[0] + xq1 * wq_[3] + xq2 * wq_[6];
    const float Q1 = xq0 * wq_[1] + xq1 * wq_[4] + xq2 * wq_[7];
    const float Q2 = xq0 * wq_[2] + xq1 * wq_[5] + xq2 * wq_[8];
    const float cc = 0.5773502691896258f * 1.4426950408889634f; // 1/sqrt(3) * log2(e)
    const float u0 = (Q0 * wk_[0] + Q1 * wk_[1] + Q2 * wk_[2]) * cc;
    const float u1 = (Q0 * wk_[3] + Q1 * wk_[4] + Q2 * wk_[5]) * cc;
    const float u2 = (Q0 * wk_[6] + Q1 * wk_[7] + Q2 * wk_[8]) * cc;

    // inner loop over this part's 512 keys: 4 keys per iter via 3x float4
    float l = 0.f, a0 = 0.f, a1 = 0.f, a2 = 0.f;
    const float4* xv = (const float4*)xs + part * (KPL * 3 / 4);
#pragma unroll 4
    for (int i = 0; i < KPL / 4; ++i) {
        const float4 c0 = xv[i * 3 + 0];
        const float4 c1 = xv[i * 3 + 1];
        const float4 c2 = xv[i * 3 + 2];
        // keys: k0=(c0.x,c0.y,c0.z) k1=(c0.w,c1.x,c1.y) k2=(c1.z,c1.w,c2.x) k3=(c2.y,c2.z,c2.w)
        const float s0 = u0 * c0.x + u1 * c0.y + u2 * c0.z;
        const float s1 = u0 * c0.w + u1 * c1.x + u2 * c1.y;
        const float s2 = u0 * c1.z + u1 * c1.w + u2 * c2.x;
        const float s3 = u0 * c2.y + u1 * c2.z + u2 * c2.w;
        const float p0 = exp2_fast(s0);
        const float p1 = exp2_fast(s1);
        const float p2 = exp2_fast(s2);
        const float p3 = exp2_fast(s3);
        l  += p0 + p1 + p2 + p3;
        a0 += p0 * c0.x + p1 * c0.w + p2 * c1.z + p3 * c2.y;
        a1 += p0 * c0.y + p1 * c1.x + p2 * c1.w + p3 * c2.z;
        a2 += p0 * c0.z + p1 * c1.y + p2 * c2.x + p3 * c2.w;
    }

    // merge the 4 k-parts (adjacent lanes, same wave)
    l  += __shfl_xor(l, 1);  l  += __shfl_xor(l, 2);
    a0 += __shfl_xor(a0, 1); a0 += __shfl_xor(a0, 2);
    a1 += __shfl_xor(a1, 1); a1 += __shfl_xor(a1, 2);
    a2 += __shfl_xor(a2, 1); a2 += __shfl_xor(a2, 2);

    if (part == 0) {
        const float inv = 1.0f / l;
        const float r0 = a0 * inv, r1 = a1 * inv, r2 = a2 * inv;
        // ctx = (a/l) @ Wv
        const float o0 = r0 * wv_[0] + r1 * wv_[3] + r2 * wv_[6];
        const float o1 = r0 * wv_[1] + r1 * wv_[4] + r2 * wv_[7];
        const float o2 = r0 * wv_[2] + r1 * wv_[5] + r2 * wv_[8];
        const int o = bh * (SEQ * 3) + q * 3;
        const int second = NB * NH * SEQ * 3;  // 196608
        out[o + 0] = o0; out[o + 1] = o1; out[o + 2] = o2;
        out[o + second + 0] = o0; out[o + second + 1] = o1; out[o + second + 2] = o2;
    }
}

extern "C" void kernel_launch(void* const* d_in, const int* in_sizes, int n_in,
                              void* d_out, int out_size, void* d_ws, size_t ws_size,
                              hipStream_t stream) {
    const float* x  = (const float*)d_in[0];
    const float* Wq = (const float*)d_in[1];
    const float* Wk = (const float*)d_in[2];
    const float* Wv = (const float*)d_in[3];
    float* out = (float*)d_out;
    (void)in_sizes; (void)n_in; (void)d_ws; (void)ws_size; (void)out_size;

    const int grid = NB * NH * (SEQ / NQ);  // 1024 blocks
    attn_d3_kernel<<<grid, 256, 0, stream>>>(x, Wq, Wk, Wv, out);
}

// Round 2
// 43.835 us; speedup vs baseline: 1.7841x; 1.7841x over previous
//
#include <hip/hip_runtime.h>

#define SEQ 2048
#define NH 8
#define NB 4
#define NQ 64           // queries per block (one per lane)
#define NWAVE 4         // waves per block; wave w owns keys [w*512, w*512+512)
#define KPL (SEQ / NWAVE)

__device__ __forceinline__ float exp2_fast(float x) {
    float r;
    asm("v_exp_f32 %0, %1" : "=v"(r) : "v"(x));
    return r;
}

__global__ __launch_bounds__(256, 4)
void attn_d3_kernel(const float* __restrict__ x,
                    const float* __restrict__ Wq,
                    const float* __restrict__ Wk,
                    const float* __restrict__ Wv,
                    float* __restrict__ out) {
    __shared__ float xs[SEQ * 3];          // 24 KB: x for this batch b
    __shared__ float red[NWAVE][NQ][4];    // 4 KB: cross-wave partials

    const int blk = blockIdx.x;
    const int qb  = blk & 31;       // 32 query-tiles per (b,h)
    const int bh  = blk >> 5;       // 0..31
    const int h   = bh & 7;
    const int b   = bh >> 3;

    const float* xb = x + b * (SEQ * 3);

    // stage x_b into LDS (float4, coalesced)
    {
        const float4* xg = (const float4*)xb;
        float4* xl = (float4*)xs;
        for (int i = threadIdx.x; i < (SEQ * 3 / 4); i += 256)
            xl[i] = xg[i];
    }

    // per-head 3x3 weights (h is wave-uniform -> scalar loads)
    const float* wqp = Wq + h * 9;
    const float* wkp = Wk + h * 9;
    const float* wvp = Wv + h * 9;
    float wq_[9], wk_[9], wv_[9];
#pragma unroll
    for (int i = 0; i < 9; ++i) { wq_[i] = wqp[i]; wk_[i] = wkp[i]; wv_[i] = wvp[i]; }

    __syncthreads();

    const int lane = threadIdx.x & 63;   // query within tile
    const int wv_id = threadIdx.x >> 6;  // key-part 0..3
    const int q    = qb * NQ + lane;

    // u = (x_q Wq) Wk^T * scale * log2(e)  -> scores in log2 domain
    const float xq0 = xs[q * 3 + 0], xq1 = xs[q * 3 + 1], xq2 = xs[q * 3 + 2];
    const float Q0 = xq0 * wq_[0] + xq1 * wq_[3] + xq2 * wq_[6];
    const float Q1 = xq0 * wq_[1] + xq1 * wq_[4] + xq2 * wq_[7];
    const float Q2 = xq0 * wq_[2] + xq1 * wq_[5] + xq2 * wq_[8];
    const float cc = 0.5773502691896258f * 1.4426950408889634f; // 1/sqrt(3)*log2(e)
    const float u0 = (Q0 * wk_[0] + Q1 * wk_[1] + Q2 * wk_[2]) * cc;
    const float u1 = (Q0 * wk_[3] + Q1 * wk_[4] + Q2 * wk_[5]) * cc;
    const float u2 = (Q0 * wk_[6] + Q1 * wk_[7] + Q2 * wk_[8]) * cc;

    // inner loop: this wave's 512 keys; all lanes read SAME LDS addr (broadcast)
    float l = 0.f, a0 = 0.f, a1 = 0.f, a2 = 0.f;
    const float4* xv = (const float4*)xs + wv_id * (KPL * 3 / 4);
#pragma unroll 4
    for (int i = 0; i < KPL / 4; ++i) {
        const float4 c0 = xv[i * 3 + 0];
        const float4 c1 = xv[i * 3 + 1];
        const float4 c2 = xv[i * 3 + 2];
        // keys: k0=(c0.x,c0.y,c0.z) k1=(c0.w,c1.x,c1.y) k2=(c1.z,c1.w,c2.x) k3=(c2.y,c2.z,c2.w)
        const float s0 = u0 * c0.x + u1 * c0.y + u2 * c0.z;
        const float s1 = u0 * c0.w + u1 * c1.x + u2 * c1.y;
        const float s2 = u0 * c1.z + u1 * c1.w + u2 * c2.x;
        const float s3 = u0 * c2.y + u1 * c2.z + u2 * c2.w;
        const float p0 = exp2_fast(s0);
        const float p1 = exp2_fast(s1);
        const float p2 = exp2_fast(s2);
        const float p3 = exp2_fast(s3);
        l  += (p0 + p1) + (p2 + p3);
        a0 += p0 * c0.x + p1 * c0.w + p2 * c1.z + p3 * c2.y;
        a1 += p0 * c0.y + p1 * c1.x + p2 * c1.w + p3 * c2.z;
        a2 += p0 * c0.z + p1 * c1.y + p2 * c2.x + p3 * c2.w;
    }

    // cross-wave merge via LDS (one float4 per thread)
    red[wv_id][lane][0] = l;
    red[wv_id][lane][1] = a0;
    red[wv_id][lane][2] = a1;
    red[wv_id][lane][3] = a2;
    __syncthreads();

    if (wv_id == 0) {
        float L = 0.f, A0 = 0.f, A1 = 0.f, A2 = 0.f;
#pragma unroll
        for (int w = 0; w < NWAVE; ++w) {
            const float4 r = *(const float4*)&red[w][lane][0];
            L += r.x; A0 += r.y; A1 += r.z; A2 += r.w;
        }
        const float inv = 1.0f / L;
        const float r0 = A0 * inv, r1 = A1 * inv, r2 = A2 * inv;
        const float o0 = r0 * wv_[0] + r1 * wv_[3] + r2 * wv_[6];
        const float o1 = r0 * wv_[1] + r1 * wv_[4] + r2 * wv_[7];
        const float o2 = r0 * wv_[2] + r1 * wv_[5] + r2 * wv_[8];
        const int o = bh * (SEQ * 3) + q * 3;
        const int second = NB * NH * SEQ * 3;  // 196608
        out[o + 0] = o0; out[o + 1] = o1; out[o + 2] = o2;
        out[o + second + 0] = o0; out[o + second + 1] = o1; out[o + second + 2] = o2;
    }
}

extern "C" void kernel_launch(void* const* d_in, const int* in_sizes, int n_in,
                              void* d_out, int out_size, void* d_ws, size_t ws_size,
                              hipStream_t stream) {
    const float* x  = (const float*)d_in[0];
    const float* Wq = (const float*)d_in[1];
    const float* Wk = (const float*)d_in[2];
    const float* Wv = (const float*)d_in[3];
    float* out = (float*)d_out;
    (void)in_sizes; (void)n_in; (void)d_ws; (void)ws_size; (void)out_size;

    const int grid = NB * NH * (SEQ / NQ);  // 1024 blocks
    attn_d3_kernel<<<grid, 256, 0, stream>>>(x, Wq, Wk, Wv, out);
}